// Round 2
// baseline (267.088 us; speedup 1.0000x reference)
//
#include <hip/hip_runtime.h>
#include <stdint.h>

#define HID 30
#define NCLS 10
#define SEQ 784
#define NBATCH 16384
#define TCH 112      // time steps per LDS stage
#define NSTAGE 7     // 7 * 112 = 784
#define XPAD 116     // padded LDS row stride in floats

typedef _Float16 f16x8 __attribute__((ext_vector_type(8)));
typedef _Float16 f16x2 __attribute__((ext_vector_type(2)));
typedef float f32x4 __attribute__((ext_vector_type(4)));
typedef uint32_t u32x4 __attribute__((ext_vector_type(4)));

static __device__ __forceinline__ f16x8 mkfrag16(uint32_t a, uint32_t b, uint32_t c, uint32_t d) {
    u32x4 t = {a, b, c, d};
    return __builtin_bit_cast(f16x8, t);
}

// Build the pair as an f16x2 vector so LLVM reliably emits v_pack_b32_f16
// (the shift/or formulation risks lshl+or codegen).
static __device__ __forceinline__ uint32_t pkf16(_Float16 lo, _Float16 hi) {
    f16x2 v = {lo, hi};
    return __builtin_bit_cast(uint32_t, v);
}

// RNE f32->f16 pair pack. RNE is REQUIRED on the recurrent path (R8: RTZ+bias
// compensation diverged 100x).
static __device__ __forceinline__ uint32_t pk_rne(float a, float b) {
    return pkf16((_Float16)a, (_Float16)b);
}

// RTZ fine for one-shot x injection (non-recurrent)
static __device__ __forceinline__ uint32_t pkrtz(float a, float b) {
    return __builtin_bit_cast(uint32_t, __builtin_amdgcn_cvt_pkrtz(a, b));
}

// packed modReLU on an f16 pair: h = sign(z) * max(|z| + b, 0)
static __device__ __forceinline__ uint32_t modrelu_pk(uint32_t z, uint32_t bp) {
    const f16x2 zero2 = {(_Float16)0.f, (_Float16)0.f};
    f16x2 t = __builtin_bit_cast(f16x2, z & 0x7FFF7FFFu) + __builtin_bit_cast(f16x2, bp);
    t = __builtin_elementwise_max(t, zero2);
    const uint32_t tb = __builtin_bit_cast(uint32_t, t);
    return (tb & 0x7FFF7FFFu) | (z & 0x80008000u);   // -> v_bfi_b32
}

static __device__ __forceinline__ uint32_t pkmax(uint32_t a, uint32_t b) {
    return __builtin_bit_cast(uint32_t,
        __builtin_elementwise_max(__builtin_bit_cast(f16x2, a), __builtin_bit_cast(f16x2, b)));
}

static __device__ __forceinline__ uint32_t scale_mul(uint32_t v, uint32_t sc32) {
    return __builtin_bit_cast(uint32_t,
        __builtin_bit_cast(f16x2, v) * __builtin_bit_cast(f16x2, sc32));
}

// R9: 1 wave per SIMD is the occupancy we get (1024 SIMDs, batch/16 = 1024
// waves). The wave is latency-bound: ~30% of each step was exposed stall.
// This version runs TWO independent 16-column recurrence chains per wave
// (grid 512): chain B's instructions fill chain A's MFMA/cvt latency bubbles.
// Per-column math is IDENTICAL to the single-chain version.
__launch_bounds__(64, 1)
__global__ void rnn_scan_kernel(const float* __restrict__ inp,
                                const float* __restrict__ W_ih,
                                const float* __restrict__ W_hh,
                                const float* __restrict__ b_mod,
                                const float* __restrict__ W_lin,
                                const float* __restrict__ b_lin,
                                float* __restrict__ out)
{
    __shared__ __align__(16) float xs_lds[32 * XPAD];

    const int lane = threadIdx.x;   // one wave per block
    const int q = lane >> 4;        // k-quad: lane holds k = 8q..8q+7 of A/B frags
    const int n = lane & 15;        // batch column within a 16-batch tile
    const int b0 = blockIdx.x * 32; // 32 batch rows per block (2 chains x 16)

    // ---- A fragments: W_aug [32x32], row-permuted so D->B is lane-local ----
    // W_aug[i][j] = W_hh[i][j] (i,j<30); W_aug[i][30] = W_ih[i]; else 0.
    // Shared by both chains.
    const int i1 = 8 * (n >> 2) + (n & 3);
    const int i2 = i1 + 4;

    uint32_t a1h[4], a1m[4], a2h[4], a2m[4];
    #pragma unroll
    for (int p = 0; p < 4; ++p) {
        _Float16 h1[2], m1[2], h2[2], m2[2];
        #pragma unroll
        for (int e = 0; e < 2; ++e) {
            const int j = 8 * q + 2 * p + e;
            float w1 = 0.f, w2 = 0.f;
            if (j < HID) {
                w1 = W_hh[i1 * HID + j];
                if (i2 < HID) w2 = W_hh[i2 * HID + j];
            } else if (j == HID) {
                w1 = W_ih[i1];
                if (i2 < HID) w2 = W_ih[i2];
            }
            h1[e] = (_Float16)w1; m1[e] = (_Float16)(w1 - (float)h1[e]);
            h2[e] = (_Float16)w2; m2[e] = (_Float16)(w2 - (float)h2[e]);
        }
        a1h[p] = pkf16(h1[0], h1[1]); a1m[p] = pkf16(m1[0], m1[1]);
        a2h[p] = pkf16(h2[0], h2[1]); a2m[p] = pkf16(m2[0], m2[1]);
    }
    const f16x8 A1h = mkfrag16(a1h[0], a1h[1], a1h[2], a1h[3]);
    const f16x8 A1m = mkfrag16(a1m[0], a1m[1], a1m[2], a1m[3]);
    const f16x8 A2h = mkfrag16(a2h[0], a2h[1], a2h[2], a2h[3]);
    const f16x8 A2m = mkfrag16(a2m[0], a2m[1], a2m[2], a2m[3]);

    // b_mod packed pairs, one copy per chain (each chain scales independently)
    uint32_t bSpA[4], bSpB[4];
    #pragma unroll
    for (int p = 0; p < 4; ++p) {
        const int ja = 8 * q + 2 * p;
        const int jb = ja + 1;
        const float ba = (ja < HID) ? b_mod[ja] : 0.f;
        const float bb = (jb < HID) ? b_mod[jb] : 0.f;
        const uint32_t v = pk_rne(ba, bb);
        bSpA[p] = v;
        bSpB[p] = v;
    }

    // packed f16 state per chain; q3's hp[3] is the x-injection slot.
    uint32_t hpA[4] = {0u, 0u, 0u, 0u};
    uint32_t hpB[4] = {0u, 0u, 0u, 0u};
    int xinvA = 0, xinvB = 0;
    int pendA = 15, pendB = 15;   // pending scale field; identity for window 0

    const bool isq3 = (q == 3);
    const f32x4 z4 = {0.f, 0.f, 0.f, 0.f};

    // 8 recurrence steps for BOTH chains, explicitly interleaved so the
    // scheduler fills each chain's MFMA->cvt latency with the other's work.
    auto do8x2 = [&](const uint32_t* xa, const uint32_t* xb) {
        #pragma unroll
        for (int tt = 0; tt < 8; ++tt) {
            const f16x8 BA = mkfrag16(hpA[0], hpA[1], hpA[2], hpA[3]);
            const f16x8 BB = mkfrag16(hpB[0], hpB[1], hpB[2], hpB[3]);
            f32x4 d1A = __builtin_amdgcn_mfma_f32_16x16x32_f16(A1h, BA, z4, 0, 0, 0);
            f32x4 d2A = __builtin_amdgcn_mfma_f32_16x16x32_f16(A2h, BA, z4, 0, 0, 0);
            f32x4 d1B = __builtin_amdgcn_mfma_f32_16x16x32_f16(A1h, BB, z4, 0, 0, 0);
            f32x4 d2B = __builtin_amdgcn_mfma_f32_16x16x32_f16(A2h, BB, z4, 0, 0, 0);
            // C->D accumulation chaining is HW-forwarded (full rate); keep it.
            d1A = __builtin_amdgcn_mfma_f32_16x16x32_f16(A1m, BA, d1A, 0, 0, 0);
            d2A = __builtin_amdgcn_mfma_f32_16x16x32_f16(A2m, BA, d2A, 0, 0, 0);
            d1B = __builtin_amdgcn_mfma_f32_16x16x32_f16(A1m, BB, d1B, 0, 0, 0);
            d2B = __builtin_amdgcn_mfma_f32_16x16x32_f16(A2m, BB, d2B, 0, 0, 0);

            hpA[0] = modrelu_pk(pk_rne(d1A[0], d1A[1]), bSpA[0]);
            hpA[1] = modrelu_pk(pk_rne(d1A[2], d1A[3]), bSpA[1]);
            hpA[2] = modrelu_pk(pk_rne(d2A[0], d2A[1]), bSpA[2]);
            const uint32_t mr3A = modrelu_pk(pk_rne(d2A[2], d2A[3]), bSpA[3]);
            hpA[3] = isq3 ? xa[(tt + 1) & 7] : mr3A;

            hpB[0] = modrelu_pk(pk_rne(d1B[0], d1B[1]), bSpB[0]);
            hpB[1] = modrelu_pk(pk_rne(d1B[2], d1B[3]), bSpB[1]);
            hpB[2] = modrelu_pk(pk_rne(d2B[0], d2B[1]), bSpB[2]);
            const uint32_t mr3B = modrelu_pk(pk_rne(d2B[2], d2B[3]), bSpB[3]);
            hpB[3] = isq3 ? xb[(tt + 1) & 7] : mr3B;
        }
    };

    for (int s = 0; s < NSTAGE; ++s) {
        // ---- stage TCH steps of inputs for 32 batch rows into LDS ----
        #pragma unroll
        for (int r = 0; r < 14; ++r) {
            const int idx = r * 64 + lane;
            const int bl = idx / 28;
            const int t4 = idx % 28;
            const float4 v = *(const float4*)(inp + (size_t)(b0 + bl) * SEQ + s * TCH + t4 * 4);
            *(float4*)(&xs_lds[bl * XPAD + t4 * 4]) = v;
        }
        __syncthreads();

        const float* xrowA = &xs_lds[n * XPAD];
        const float* xrowB = &xs_lds[(16 + n) * XPAD];
        float4 xvA0 = *(const float4*)(xrowA);
        float4 xvA1 = *(const float4*)(xrowA + 4);
        float4 xvB0 = *(const float4*)(xrowB);
        float4 xvB1 = *(const float4*)(xrowB + 4);

        for (int t16 = 0; t16 < 7; ++t16) {   // 7 * 16 = 112 steps per stage
            // ---- APPLY pending scale (computed from state 16 steps ago) ----
            const uint32_t scA = (uint32_t)pendA * 0x04000400u;  // f16x2 2^(field-15)
            const uint32_t scB = (uint32_t)pendB * 0x04000400u;
            #pragma unroll
            for (int p = 0; p < 4; ++p) { hpA[p] = scale_mul(hpA[p], scA); hpB[p] = scale_mul(hpB[p], scB); }
            #pragma unroll
            for (int p = 0; p < 4; ++p) { bSpA[p] = scale_mul(bSpA[p], scA); bSpB[p] = scale_mul(bSpB[p], scB); }
            xinvA += pendA - 15;
            xinvB += pendB - 15;

            const float facA = __uint_as_float((uint32_t)(127 + xinvA) << 23);
            const float facB = __uint_as_float((uint32_t)(127 + xinvB) << 23);

            uint32_t mxA, mxB;

            // ===== first 8-step half =====
            {
                const int toff = t16 * 16 + 8;    // second half's x (always in range)
                const float4 xnA0 = *(const float4*)(xrowA + toff);
                const float4 xnA1 = *(const float4*)(xrowA + toff + 4);
                const float4 xnB0 = *(const float4*)(xrowB + toff);
                const float4 xnB1 = *(const float4*)(xrowB + toff + 4);

                uint32_t xa[8], xb[8];
                xa[0] = pkrtz(xvA0.x * facA, 0.f); xa[1] = pkrtz(xvA0.y * facA, 0.f);
                xa[2] = pkrtz(xvA0.z * facA, 0.f); xa[3] = pkrtz(xvA0.w * facA, 0.f);
                xa[4] = pkrtz(xvA1.x * facA, 0.f); xa[5] = pkrtz(xvA1.y * facA, 0.f);
                xa[6] = pkrtz(xvA1.z * facA, 0.f); xa[7] = pkrtz(xvA1.w * facA, 0.f);
                xb[0] = pkrtz(xvB0.x * facB, 0.f); xb[1] = pkrtz(xvB0.y * facB, 0.f);
                xb[2] = pkrtz(xvB0.z * facB, 0.f); xb[3] = pkrtz(xvB0.w * facB, 0.f);
                xb[4] = pkrtz(xvB1.x * facB, 0.f); xb[5] = pkrtz(xvB1.y * facB, 0.f);
                xb[6] = pkrtz(xvB1.z * facB, 0.f); xb[7] = pkrtz(xvB1.w * facB, 0.f);
                hpA[3] = isq3 ? xa[0] : hpA[3];
                hpB[3] = isq3 ? xb[0] : hpB[3];

                // ---- SAMPLE max for the NEXT window (16-step staleness safe).
                // Butterfly split across the window: issue each shfl ~8 steps
                // before its consumer so the DS latency hides under do8x2.
                mxA = pkmax(pkmax(hpA[0] & 0x7FFF7FFFu, hpA[1] & 0x7FFF7FFFu),
                            pkmax(hpA[2] & 0x7FFF7FFFu, hpA[3] & 0x7FFF7FFFu));
                mxB = pkmax(pkmax(hpB[0] & 0x7FFF7FFFu, hpB[1] & 0x7FFF7FFFu),
                            pkmax(hpB[2] & 0x7FFF7FFFu, hpB[3] & 0x7FFF7FFFu));
                const uint32_t shA1 = (uint32_t)__shfl_xor((int)mxA, 16);
                const uint32_t shB1 = (uint32_t)__shfl_xor((int)mxB, 16);

                do8x2(xa, xb);

                mxA = pkmax(mxA, shA1);
                mxB = pkmax(mxB, shB1);
                xvA0 = xnA0; xvA1 = xnA1; xvB0 = xnB0; xvB1 = xnB1;
            }
            const uint32_t shA2 = (uint32_t)__shfl_xor((int)mxA, 32);
            const uint32_t shB2 = (uint32_t)__shfl_xor((int)mxB, 32);

            // ===== second 8-step half (same fac; no renorm) =====
            {
                const int toff = (t16 < 6) ? (t16 + 1) * 16 : 0;   // dummy 0 on last
                const float4 xnA0 = *(const float4*)(xrowA + toff);
                const float4 xnA1 = *(const float4*)(xrowA + toff + 4);
                const float4 xnB0 = *(const float4*)(xrowB + toff);
                const float4 xnB1 = *(const float4*)(xrowB + toff + 4);

                uint32_t xa[8], xb[8];
                xa[0] = pkrtz(xvA0.x * facA, 0.f); xa[1] = pkrtz(xvA0.y * facA, 0.f);
                xa[2] = pkrtz(xvA0.z * facA, 0.f); xa[3] = pkrtz(xvA0.w * facA, 0.f);
                xa[4] = pkrtz(xvA1.x * facA, 0.f); xa[5] = pkrtz(xvA1.y * facA, 0.f);
                xa[6] = pkrtz(xvA1.z * facA, 0.f); xa[7] = pkrtz(xvA1.w * facA, 0.f);
                xb[0] = pkrtz(xvB0.x * facB, 0.f); xb[1] = pkrtz(xvB0.y * facB, 0.f);
                xb[2] = pkrtz(xvB0.z * facB, 0.f); xb[3] = pkrtz(xvB0.w * facB, 0.f);
                xb[4] = pkrtz(xvB1.x * facB, 0.f); xb[5] = pkrtz(xvB1.y * facB, 0.f);
                xb[6] = pkrtz(xvB1.z * facB, 0.f); xb[7] = pkrtz(xvB1.w * facB, 0.f);
                hpA[3] = isq3 ? xa[0] : hpA[3];
                hpB[3] = isq3 ? xb[0] : hpB[3];

                do8x2(xa, xb);

                xvA0 = xnA0; xvA1 = xnA1; xvB0 = xnB0; xvB1 = xnB1;
            }

            // finish butterfly, derive next window's pending scale field
            mxA = pkmax(mxA, shA2);
            mxB = pkmax(mxB, shB2);
            const uint32_t eA = max(mxA & 0xFFFFu, mxA >> 16);
            const uint32_t eB = max(mxB & 0xFFFFu, mxB >> 16);
            pendA = min(max(25 - (int)(eA >> 10), 1), 20);
            pendB = min(max(25 - (int)(eB >> 10), 1), 20);
        }
        __syncthreads();
    }

    // ---- final linear: logits = S * (h_hat @ W_lin^T) + b_lin ----
    const float SA = __uint_as_float((uint32_t)(127 - xinvA) << 23);
    const float SB = __uint_as_float((uint32_t)(127 - xinvB) << 23);
    float hfA[8], hfB[8];
    #pragma unroll
    for (int p = 0; p < 4; ++p) {
        const f16x2 va = __builtin_bit_cast(f16x2, hpA[p]);
        const f16x2 vb = __builtin_bit_cast(f16x2, hpB[p]);
        hfA[2 * p] = (float)va.x; hfA[2 * p + 1] = (float)va.y;
        hfB[2 * p] = (float)vb.x; hfB[2 * p + 1] = (float)vb.y;
    }
    float accA[NCLS], accB[NCLS];
    #pragma unroll
    for (int c = 0; c < NCLS; ++c) {
        float pA = 0.f, pB = 0.f;
        #pragma unroll
        for (int k = 0; k < 8; ++k) {
            const int j = 8 * q + k;
            if (j < HID) {
                const float w = W_lin[c * HID + j];
                pA += w * hfA[k];
                pB += w * hfB[k];
            }
        }
        pA += __shfl_xor(pA, 16, 64);
        pA += __shfl_xor(pA, 32, 64);
        pB += __shfl_xor(pB, 16, 64);
        pB += __shfl_xor(pB, 32, 64);
        accA[c] = pA * SA + b_lin[c];
        accB[c] = pB * SB + b_lin[c];
    }
    if (q == 0) {
        #pragma unroll
        for (int c = 0; c < NCLS; ++c) {
            out[(size_t)(b0 + n) * NCLS + c] = accA[c];
            out[(size_t)(b0 + 16 + n) * NCLS + c] = accB[c];
        }
    }
}

extern "C" void kernel_launch(void* const* d_in, const int* in_sizes, int n_in,
                              void* d_out, int out_size, void* d_ws, size_t ws_size,
                              hipStream_t stream) {
    const float* inp   = (const float*)d_in[0];
    const float* W_ih  = (const float*)d_in[1];
    const float* W_hh  = (const float*)d_in[2];
    const float* b_mod = (const float*)d_in[3];
    const float* W_lin = (const float*)d_in[4];
    const float* b_lin = (const float*)d_in[5];
    float* out = (float*)d_out;

    dim3 grid(NBATCH / 32);  // 512 blocks x 1 wave, 2 independent 16-col chains each
    dim3 block(64);
    hipLaunchKernelGGL(rnn_scan_kernel, grid, block, 0, stream,
                       inp, W_ih, W_hh, b_mod, W_lin, b_lin, out);
}

// Round 3
// 257.584 us; speedup vs baseline: 1.0369x; 1.0369x over previous
//
#include <hip/hip_runtime.h>
#include <stdint.h>

#define HID 30
#define NCLS 10
#define SEQ 784
#define NBATCH 16384
#define TCH 112      // time steps per LDS stage
#define NSTAGE 7     // 7 * 112 = 784
#define XPAD 116     // padded LDS row stride in floats

typedef _Float16 f16x8 __attribute__((ext_vector_type(8)));
typedef _Float16 f16x2 __attribute__((ext_vector_type(2)));
typedef float f32x4 __attribute__((ext_vector_type(4)));
typedef uint32_t u32x4 __attribute__((ext_vector_type(4)));

static __device__ __forceinline__ f16x8 mkfrag16(uint32_t a, uint32_t b, uint32_t c, uint32_t d) {
    u32x4 t = {a, b, c, d};
    return __builtin_bit_cast(f16x8, t);
}

static __device__ __forceinline__ uint32_t pkf16(_Float16 lo, _Float16 hi) {
    f16x2 v = {lo, hi};
    return __builtin_bit_cast(uint32_t, v);
}

// RNE f32->f16 pair pack. RNE is REQUIRED on the recurrent path (R8: RTZ+bias
// compensation diverged 100x).
static __device__ __forceinline__ uint32_t pk_rne(float a, float b) {
    return pkf16((_Float16)a, (_Float16)b);
}

// RTZ fine for one-shot x injection (non-recurrent)
static __device__ __forceinline__ uint32_t pkrtz(float a, float b) {
    return __builtin_bit_cast(uint32_t, __builtin_amdgcn_cvt_pkrtz(a, b));
}

// packed modReLU on an f16 pair: h = sign(z) * max(|z| + b, 0)
static __device__ __forceinline__ uint32_t modrelu_pk(uint32_t z, uint32_t bp) {
    const f16x2 zero2 = {(_Float16)0.f, (_Float16)0.f};
    f16x2 t = __builtin_bit_cast(f16x2, z & 0x7FFF7FFFu) + __builtin_bit_cast(f16x2, bp);
    t = __builtin_elementwise_max(t, zero2);
    const uint32_t tb = __builtin_bit_cast(uint32_t, t);
    return (tb & 0x7FFF7FFFu) | (z & 0x80008000u);   // -> v_bfi_b32
}

static __device__ __forceinline__ uint32_t pkmax(uint32_t a, uint32_t b) {
    return __builtin_bit_cast(uint32_t,
        __builtin_elementwise_max(__builtin_bit_cast(f16x2, a), __builtin_bit_cast(f16x2, b)));
}

static __device__ __forceinline__ uint32_t scale_mul(uint32_t v, uint32_t sc32) {
    return __builtin_bit_cast(uint32_t,
        __builtin_bit_cast(f16x2, v) * __builtin_bit_cast(f16x2, sc32));
}

// R10: two independent 16-col chains per wave. R9's 2-chain attempt used
// address-taken xa[8]/xb[8] arrays (lambda pointer args) -> suspected scratch
// demotion -> perfect 2x serialization (222us, VGPR only 84, FETCH unchanged).
// This version: NO address-taken locals on the hot path. All per-half x values
// are named scalars passed BY VALUE; chains interleaved statement-by-statement.
// Per-column math is IDENTICAL to the verified 114us single-chain kernel.
__launch_bounds__(64, 1)
__global__ void rnn_scan_kernel(const float* __restrict__ inp,
                                const float* __restrict__ W_ih,
                                const float* __restrict__ W_hh,
                                const float* __restrict__ b_mod,
                                const float* __restrict__ W_lin,
                                const float* __restrict__ b_lin,
                                float* __restrict__ out)
{
    __shared__ __align__(16) float xs_lds[32 * XPAD];

    const int lane = threadIdx.x;   // one wave per block
    const int q = lane >> 4;        // k-quad: lane holds k = 8q..8q+7 of A/B frags
    const int n = lane & 15;        // batch column within a 16-batch tile
    const int b0 = blockIdx.x * 32; // 32 batch rows per block (2 chains x 16)

    // ---- A fragments: W_aug [32x32], row-permuted so D->B is lane-local ----
    // W_aug[i][j] = W_hh[i][j] (i,j<30); W_aug[i][30] = W_ih[i]; else 0.
    // Shared by both chains. A = Ah + Am (2-way f16 RNE split, ~21-bit).
    const int i1 = 8 * (n >> 2) + (n & 3);
    const int i2 = i1 + 4;

    uint32_t a1h[4], a1m[4], a2h[4], a2m[4];
    #pragma unroll
    for (int p = 0; p < 4; ++p) {
        _Float16 h1[2], m1[2], h2[2], m2[2];
        #pragma unroll
        for (int e = 0; e < 2; ++e) {
            const int j = 8 * q + 2 * p + e;
            float w1 = 0.f, w2 = 0.f;
            if (j < HID) {
                w1 = W_hh[i1 * HID + j];
                if (i2 < HID) w2 = W_hh[i2 * HID + j];
            } else if (j == HID) {
                w1 = W_ih[i1];
                if (i2 < HID) w2 = W_ih[i2];
            }
            h1[e] = (_Float16)w1; m1[e] = (_Float16)(w1 - (float)h1[e]);
            h2[e] = (_Float16)w2; m2[e] = (_Float16)(w2 - (float)h2[e]);
        }
        a1h[p] = pkf16(h1[0], h1[1]); a1m[p] = pkf16(m1[0], m1[1]);
        a2h[p] = pkf16(h2[0], h2[1]); a2m[p] = pkf16(m2[0], m2[1]);
    }
    const f16x8 A1h = mkfrag16(a1h[0], a1h[1], a1h[2], a1h[3]);
    const f16x8 A1m = mkfrag16(a1m[0], a1m[1], a1m[2], a1m[3]);
    const f16x8 A2h = mkfrag16(a2h[0], a2h[1], a2h[2], a2h[3]);
    const f16x8 A2m = mkfrag16(a2m[0], a2m[1], a2m[2], a2m[3]);

    // b_mod packed pairs, one copy per chain (each chain scales independently)
    uint32_t bSpA[4], bSpB[4];
    #pragma unroll
    for (int p = 0; p < 4; ++p) {
        const int ja = 8 * q + 2 * p;
        const int jb = ja + 1;
        const float ba = (ja < HID) ? b_mod[ja] : 0.f;
        const float bb = (jb < HID) ? b_mod[jb] : 0.f;
        const uint32_t v = pk_rne(ba, bb);
        bSpA[p] = v;
        bSpB[p] = v;
    }

    // packed f16 state per chain; q3's hp[3] is the x-injection slot.
    uint32_t hpA[4] = {0u, 0u, 0u, 0u};
    uint32_t hpB[4] = {0u, 0u, 0u, 0u};
    int xinvA = 0, xinvB = 0;
    int pendA = 15, pendB = 15;   // pending scale field; identity for window 0

    const bool isq3 = (q == 3);
    const f32x4 z4 = {0.f, 0.f, 0.f, 0.f};

    // One recurrence step for BOTH chains, finely interleaved. xna/xnb are the
    // NEXT step's x injections (by value -- no address-taken storage).
    auto step2 = [&](uint32_t xna, uint32_t xnb) {
        const f16x8 BA = mkfrag16(hpA[0], hpA[1], hpA[2], hpA[3]);
        const f16x8 BB = mkfrag16(hpB[0], hpB[1], hpB[2], hpB[3]);
        f32x4 d1A = __builtin_amdgcn_mfma_f32_16x16x32_f16(A1h, BA, z4, 0, 0, 0);
        f32x4 d1B = __builtin_amdgcn_mfma_f32_16x16x32_f16(A1h, BB, z4, 0, 0, 0);
        f32x4 d2A = __builtin_amdgcn_mfma_f32_16x16x32_f16(A2h, BA, z4, 0, 0, 0);
        f32x4 d2B = __builtin_amdgcn_mfma_f32_16x16x32_f16(A2h, BB, z4, 0, 0, 0);
        d1A = __builtin_amdgcn_mfma_f32_16x16x32_f16(A1m, BA, d1A, 0, 0, 0);
        d1B = __builtin_amdgcn_mfma_f32_16x16x32_f16(A1m, BB, d1B, 0, 0, 0);
        d2A = __builtin_amdgcn_mfma_f32_16x16x32_f16(A2m, BA, d2A, 0, 0, 0);
        d2B = __builtin_amdgcn_mfma_f32_16x16x32_f16(A2m, BB, d2B, 0, 0, 0);

        hpA[0] = modrelu_pk(pk_rne(d1A[0], d1A[1]), bSpA[0]);
        hpB[0] = modrelu_pk(pk_rne(d1B[0], d1B[1]), bSpB[0]);
        hpA[1] = modrelu_pk(pk_rne(d1A[2], d1A[3]), bSpA[1]);
        hpB[1] = modrelu_pk(pk_rne(d1B[2], d1B[3]), bSpB[1]);
        hpA[2] = modrelu_pk(pk_rne(d2A[0], d2A[1]), bSpA[2]);
        hpB[2] = modrelu_pk(pk_rne(d2B[0], d2B[1]), bSpB[2]);
        const uint32_t mr3A = modrelu_pk(pk_rne(d2A[2], d2A[3]), bSpA[3]);
        const uint32_t mr3B = modrelu_pk(pk_rne(d2B[2], d2B[3]), bSpB[3]);
        hpA[3] = isq3 ? xna : mr3A;
        hpB[3] = isq3 ? xnb : mr3B;
    };

    for (int s = 0; s < NSTAGE; ++s) {
        // ---- stage TCH steps of inputs for 32 batch rows into LDS ----
        #pragma unroll
        for (int r = 0; r < 14; ++r) {
            const int idx = r * 64 + lane;
            const int bl = idx / 28;
            const int t4 = idx % 28;
            const float4 v = *(const float4*)(inp + (size_t)(b0 + bl) * SEQ + s * TCH + t4 * 4);
            *(float4*)(&xs_lds[bl * XPAD + t4 * 4]) = v;
        }
        __syncthreads();

        const float* xrowA = &xs_lds[n * XPAD];
        const float* xrowB = &xs_lds[(16 + n) * XPAD];
        float4 xvA0 = *(const float4*)(xrowA);
        float4 xvA1 = *(const float4*)(xrowA + 4);
        float4 xvB0 = *(const float4*)(xrowB);
        float4 xvB1 = *(const float4*)(xrowB + 4);

        for (int t16 = 0; t16 < 7; ++t16) {   // 7 * 16 = 112 steps per stage
            // ---- APPLY pending scale (computed from state 16 steps ago) ----
            const uint32_t scA = (uint32_t)pendA * 0x04000400u;  // f16x2 2^(field-15)
            const uint32_t scB = (uint32_t)pendB * 0x04000400u;
            #pragma unroll
            for (int p = 0; p < 4; ++p) { hpA[p] = scale_mul(hpA[p], scA); hpB[p] = scale_mul(hpB[p], scB); }
            #pragma unroll
            for (int p = 0; p < 4; ++p) { bSpA[p] = scale_mul(bSpA[p], scA); bSpB[p] = scale_mul(bSpB[p], scB); }
            xinvA += pendA - 15;
            xinvB += pendB - 15;

            const float facA = __uint_as_float((uint32_t)(127 + xinvA) << 23);
            const float facB = __uint_as_float((uint32_t)(127 + xinvB) << 23);

            uint32_t mxA, mxB;

            // ===== first 8-step half =====
            {
                const int toff = t16 * 16 + 8;    // second half's x (always in range)
                const float4 xnA0 = *(const float4*)(xrowA + toff);
                const float4 xnA1 = *(const float4*)(xrowA + toff + 4);
                const float4 xnB0 = *(const float4*)(xrowB + toff);
                const float4 xnB1 = *(const float4*)(xrowB + toff + 4);

                // named scalars only -- nothing address-taken
                const uint32_t xa0 = pkrtz(xvA0.x * facA, 0.f);
                const uint32_t xa1 = pkrtz(xvA0.y * facA, 0.f);
                const uint32_t xa2 = pkrtz(xvA0.z * facA, 0.f);
                const uint32_t xa3 = pkrtz(xvA0.w * facA, 0.f);
                const uint32_t xa4 = pkrtz(xvA1.x * facA, 0.f);
                const uint32_t xa5 = pkrtz(xvA1.y * facA, 0.f);
                const uint32_t xa6 = pkrtz(xvA1.z * facA, 0.f);
                const uint32_t xa7 = pkrtz(xvA1.w * facA, 0.f);
                const uint32_t xb0 = pkrtz(xvB0.x * facB, 0.f);
                const uint32_t xb1 = pkrtz(xvB0.y * facB, 0.f);
                const uint32_t xb2 = pkrtz(xvB0.z * facB, 0.f);
                const uint32_t xb3 = pkrtz(xvB0.w * facB, 0.f);
                const uint32_t xb4 = pkrtz(xvB1.x * facB, 0.f);
                const uint32_t xb5 = pkrtz(xvB1.y * facB, 0.f);
                const uint32_t xb6 = pkrtz(xvB1.z * facB, 0.f);
                const uint32_t xb7 = pkrtz(xvB1.w * facB, 0.f);
                hpA[3] = isq3 ? xa0 : hpA[3];   // step-0 x into the B-frag x slot
                hpB[3] = isq3 ? xb0 : hpB[3];

                // ---- SAMPLE max for the NEXT window (16-step staleness safe).
                // Butterfly split: shfl issued ~8 steps before its consumer.
                mxA = pkmax(pkmax(hpA[0] & 0x7FFF7FFFu, hpA[1] & 0x7FFF7FFFu),
                            pkmax(hpA[2] & 0x7FFF7FFFu, hpA[3] & 0x7FFF7FFFu));
                mxB = pkmax(pkmax(hpB[0] & 0x7FFF7FFFu, hpB[1] & 0x7FFF7FFFu),
                            pkmax(hpB[2] & 0x7FFF7FFFu, hpB[3] & 0x7FFF7FFFu));
                const uint32_t shA1 = (uint32_t)__shfl_xor((int)mxA, 16);
                const uint32_t shB1 = (uint32_t)__shfl_xor((int)mxB, 16);

                step2(xa1, xb1); step2(xa2, xb2); step2(xa3, xb3); step2(xa4, xb4);
                step2(xa5, xb5); step2(xa6, xb6); step2(xa7, xb7);
                step2(xa0, xb0);   // tt=7 injection is dummy (overwritten next half)

                mxA = pkmax(mxA, shA1);
                mxB = pkmax(mxB, shB1);
                xvA0 = xnA0; xvA1 = xnA1; xvB0 = xnB0; xvB1 = xnB1;
            }
            const uint32_t shA2 = (uint32_t)__shfl_xor((int)mxA, 32);
            const uint32_t shB2 = (uint32_t)__shfl_xor((int)mxB, 32);

            // ===== second 8-step half (same fac; no renorm) =====
            {
                const int toff = (t16 < 6) ? (t16 + 1) * 16 : 0;   // dummy 0 on last
                const float4 xnA0 = *(const float4*)(xrowA + toff);
                const float4 xnA1 = *(const float4*)(xrowA + toff + 4);
                const float4 xnB0 = *(const float4*)(xrowB + toff);
                const float4 xnB1 = *(const float4*)(xrowB + toff + 4);

                const uint32_t xa0 = pkrtz(xvA0.x * facA, 0.f);
                const uint32_t xa1 = pkrtz(xvA0.y * facA, 0.f);
                const uint32_t xa2 = pkrtz(xvA0.z * facA, 0.f);
                const uint32_t xa3 = pkrtz(xvA0.w * facA, 0.f);
                const uint32_t xa4 = pkrtz(xvA1.x * facA, 0.f);
                const uint32_t xa5 = pkrtz(xvA1.y * facA, 0.f);
                const uint32_t xa6 = pkrtz(xvA1.z * facA, 0.f);
                const uint32_t xa7 = pkrtz(xvA1.w * facA, 0.f);
                const uint32_t xb0 = pkrtz(xvB0.x * facB, 0.f);
                const uint32_t xb1 = pkrtz(xvB0.y * facB, 0.f);
                const uint32_t xb2 = pkrtz(xvB0.z * facB, 0.f);
                const uint32_t xb3 = pkrtz(xvB0.w * facB, 0.f);
                const uint32_t xb4 = pkrtz(xvB1.x * facB, 0.f);
                const uint32_t xb5 = pkrtz(xvB1.y * facB, 0.f);
                const uint32_t xb6 = pkrtz(xvB1.z * facB, 0.f);
                const uint32_t xb7 = pkrtz(xvB1.w * facB, 0.f);
                hpA[3] = isq3 ? xa0 : hpA[3];
                hpB[3] = isq3 ? xb0 : hpB[3];

                step2(xa1, xb1); step2(xa2, xb2); step2(xa3, xb3); step2(xa4, xb4);
                step2(xa5, xb5); step2(xa6, xb6); step2(xa7, xb7);
                step2(xa0, xb0);

                xvA0 = xnA0; xvA1 = xnA1; xvB0 = xnB0; xvB1 = xnB1;
            }

            // finish butterfly, derive next window's pending scale field
            mxA = pkmax(mxA, shA2);
            mxB = pkmax(mxB, shB2);
            const uint32_t eA = max(mxA & 0xFFFFu, mxA >> 16);
            const uint32_t eB = max(mxB & 0xFFFFu, mxB >> 16);
            pendA = min(max(25 - (int)(eA >> 10), 1), 20);
            pendB = min(max(25 - (int)(eB >> 10), 1), 20);
        }
        __syncthreads();
    }

    // ---- final linear: logits = S * (h_hat @ W_lin^T) + b_lin ----
    const float SA = __uint_as_float((uint32_t)(127 - xinvA) << 23);
    const float SB = __uint_as_float((uint32_t)(127 - xinvB) << 23);
    float hfA[8], hfB[8];
    #pragma unroll
    for (int p = 0; p < 4; ++p) {
        const f16x2 va = __builtin_bit_cast(f16x2, hpA[p]);
        const f16x2 vb = __builtin_bit_cast(f16x2, hpB[p]);
        hfA[2 * p] = (float)va.x; hfA[2 * p + 1] = (float)va.y;
        hfB[2 * p] = (float)vb.x; hfB[2 * p + 1] = (float)vb.y;
    }
    float accA[NCLS], accB[NCLS];
    #pragma unroll
    for (int c = 0; c < NCLS; ++c) {
        float pA = 0.f, pB = 0.f;
        #pragma unroll
        for (int k = 0; k < 8; ++k) {
            const int j = 8 * q + k;
            if (j < HID) {
                const float w = W_lin[c * HID + j];
                pA += w * hfA[k];
                pB += w * hfB[k];
            }
        }
        pA += __shfl_xor(pA, 16, 64);
        pA += __shfl_xor(pA, 32, 64);
        pB += __shfl_xor(pB, 16, 64);
        pB += __shfl_xor(pB, 32, 64);
        accA[c] = pA * SA + b_lin[c];
        accB[c] = pB * SB + b_lin[c];
    }
    if (q == 0) {
        #pragma unroll
        for (int c = 0; c < NCLS; ++c) {
            out[(size_t)(b0 + n) * NCLS + c] = accA[c];
            out[(size_t)(b0 + 16 + n) * NCLS + c] = accB[c];
        }
    }
}

extern "C" void kernel_launch(void* const* d_in, const int* in_sizes, int n_in,
                              void* d_out, int out_size, void* d_ws, size_t ws_size,
                              hipStream_t stream) {
    const float* inp   = (const float*)d_in[0];
    const float* W_ih  = (const float*)d_in[1];
    const float* W_hh  = (const float*)d_in[2];
    const float* b_mod = (const float*)d_in[3];
    const float* W_lin = (const float*)d_in[4];
    const float* b_lin = (const float*)d_in[5];
    float* out = (float*)d_out;

    dim3 grid(NBATCH / 32);  // 512 blocks x 1 wave, 2 independent 16-col chains each
    dim3 block(64);
    hipLaunchKernelGGL(rnn_scan_kernel, grid, block, 0, stream,
                       inp, W_ih, W_hh, b_mod, W_lin, b_lin, out);
}

// Round 4
// 219.514 us; speedup vs baseline: 1.2167x; 1.1734x over previous
//
#include <hip/hip_runtime.h>
#include <stdint.h>

#define HID 30
#define NCLS 10
#define SEQ 784
#define NBATCH 16384
#define TCH 112      // time steps per LDS stage
#define NSTAGE 7     // 7 * 112 = 784
#define XPAD 116     // padded LDS row stride in floats

typedef _Float16 f16x8 __attribute__((ext_vector_type(8)));
typedef _Float16 f16x2 __attribute__((ext_vector_type(2)));
typedef float f32x4 __attribute__((ext_vector_type(4)));
typedef uint32_t u32x4 __attribute__((ext_vector_type(4)));

static __device__ __forceinline__ f16x8 mkfrag16(uint32_t a, uint32_t b, uint32_t c, uint32_t d) {
    u32x4 t = {a, b, c, d};
    return __builtin_bit_cast(f16x8, t);
}

static __device__ __forceinline__ uint32_t pkf16(_Float16 lo, _Float16 hi) {
    f16x2 v = {lo, hi};
    return __builtin_bit_cast(uint32_t, v);
}

// RNE f32->f16 pair pack. RNE is REQUIRED on the recurrent path (R8: RTZ+bias
// compensation diverged 100x).
static __device__ __forceinline__ uint32_t pk_rne(float a, float b) {
    return pkf16((_Float16)a, (_Float16)b);
}

// RTZ fine for one-shot x injection (non-recurrent)
static __device__ __forceinline__ uint32_t pkrtz(float a, float b) {
    return __builtin_bit_cast(uint32_t, __builtin_amdgcn_cvt_pkrtz(a, b));
}

// packed modReLU on an f16 pair: h = sign(z) * max(|z| + b, 0)
static __device__ __forceinline__ uint32_t modrelu_pk(uint32_t z, uint32_t bp) {
    const f16x2 zero2 = {(_Float16)0.f, (_Float16)0.f};
    f16x2 t = __builtin_bit_cast(f16x2, z & 0x7FFF7FFFu) + __builtin_bit_cast(f16x2, bp);
    t = __builtin_elementwise_max(t, zero2);
    const uint32_t tb = __builtin_bit_cast(uint32_t, t);
    return (tb & 0x7FFF7FFFu) | (z & 0x80008000u);   // -> v_bfi_b32
}

static __device__ __forceinline__ uint32_t pkmax(uint32_t a, uint32_t b) {
    return __builtin_bit_cast(uint32_t,
        __builtin_elementwise_max(__builtin_bit_cast(f16x2, a), __builtin_bit_cast(f16x2, b)));
}

static __device__ __forceinline__ uint32_t scale_mul(uint32_t v, uint32_t sc32) {
    return __builtin_bit_cast(uint32_t,
        __builtin_bit_cast(f16x2, v) * __builtin_bit_cast(f16x2, sc32));
}

// R11: TLP instead of ILP. R10 showed 2 chains/wave is structurally capped:
// VALU ops are per-wave, so merging chains doubles per-wave VALU and can never
// beat the single-chain step time. Instead: 8 REAL batch columns per wave
// (cols 8..15 duplicate 0..7 via n&7 -- columns are independent in MFMA, all
// shfl reductions stay within a column), grid 2048 -> 8 blocks/CU -> 2 waves
// per SIMD. The ~110 cy/step of wave-private MFMA-hazard stall is filled by
// the co-resident wave via HW round-robin issue -- no compiler cooperation
// needed. Per-wave instruction stream is IDENTICAL to the verified 114us
// kernel; per-column math unchanged.
__launch_bounds__(64, 1)
__global__ void rnn_scan_kernel(const float* __restrict__ inp,
                                const float* __restrict__ W_ih,
                                const float* __restrict__ W_hh,
                                const float* __restrict__ b_mod,
                                const float* __restrict__ W_lin,
                                const float* __restrict__ b_lin,
                                float* __restrict__ out)
{
    __shared__ __align__(16) float xs_lds[8 * XPAD];

    const int lane = threadIdx.x;   // one wave per block
    const int q = lane >> 4;        // k-quad: lane holds k = 8q..8q+7 of A/B frags
    const int n = lane & 15;        // column slot; real batch col = n&7
    const int b0 = blockIdx.x * 8;  // 8 batch rows per block

    // ---- A fragments: W_aug [32x32], row-permuted so D->B is lane-local ----
    // W_aug[i][j] = W_hh[i][j] (i,j<30); W_aug[i][30] = W_ih[i]; else 0.
    // A mapping depends on (n,q) only -- unchanged by the 8-col tiling.
    const int i1 = 8 * (n >> 2) + (n & 3);
    const int i2 = i1 + 4;

    uint32_t a1h[4], a1m[4], a2h[4], a2m[4];
    #pragma unroll
    for (int p = 0; p < 4; ++p) {
        _Float16 h1[2], m1[2], h2[2], m2[2];
        #pragma unroll
        for (int e = 0; e < 2; ++e) {
            const int j = 8 * q + 2 * p + e;
            float w1 = 0.f, w2 = 0.f;
            if (j < HID) {
                w1 = W_hh[i1 * HID + j];
                if (i2 < HID) w2 = W_hh[i2 * HID + j];
            } else if (j == HID) {
                w1 = W_ih[i1];
                if (i2 < HID) w2 = W_ih[i2];
            }
            h1[e] = (_Float16)w1; m1[e] = (_Float16)(w1 - (float)h1[e]);
            h2[e] = (_Float16)w2; m2[e] = (_Float16)(w2 - (float)h2[e]);
        }
        a1h[p] = pkf16(h1[0], h1[1]); a1m[p] = pkf16(m1[0], m1[1]);
        a2h[p] = pkf16(h2[0], h2[1]); a2m[p] = pkf16(m2[0], m2[1]);
    }
    const f16x8 A1h = mkfrag16(a1h[0], a1h[1], a1h[2], a1h[3]);
    const f16x8 A1m = mkfrag16(a1m[0], a1m[1], a1m[2], a1m[3]);
    const f16x8 A2h = mkfrag16(a2h[0], a2h[1], a2h[2], a2h[3]);
    const f16x8 A2m = mkfrag16(a2m[0], a2m[1], a2m[2], a2m[3]);

    // b_mod packed pairs for this lane's 8 output rows (f16, scaled space b/S)
    uint32_t bSp[4];
    #pragma unroll
    for (int p = 0; p < 4; ++p) {
        const int ja = 8 * q + 2 * p;
        const int jb = ja + 1;
        const float ba = (ja < HID) ? b_mod[ja] : 0.f;
        const float bb = (jb < HID) ? b_mod[jb] : 0.f;
        bSp[p] = pk_rne(ba, bb);
    }

    // packed f16 state: hp[p] = (h[8q+2p], h[8q+2p+1]) in scaled space.
    // True h = S * h_hat, S = 2^(-xinv_e) per column. q3's hp[3] (rows 30,31 =
    // zero rows of W_aug) is dead state, reused as the x-injection slot so the
    // persistent state quad IS the MFMA B fragment.
    uint32_t hp[4] = {0u, 0u, 0u, 0u};
    int xinv_e = 0;
    int pend_field = 15;   // pending scale sc = 2^(field-15); identity for window 0

    const bool isq3 = (q == 3);
    const f32x4 z4 = {0.f, 0.f, 0.f, 0.f};

    // 8 recurrence steps using x values xpk[0..7] (verified step body)
    auto do8 = [&](const uint32_t* xpk) {
        #pragma unroll
        for (int tt = 0; tt < 8; ++tt) {
            const f16x8 Bh = mkfrag16(hp[0], hp[1], hp[2], hp[3]);
            f32x4 d1 = __builtin_amdgcn_mfma_f32_16x16x32_f16(A1h, Bh, z4, 0, 0, 0);
            f32x4 d2 = __builtin_amdgcn_mfma_f32_16x16x32_f16(A2h, Bh, z4, 0, 0, 0);
            d1 = __builtin_amdgcn_mfma_f32_16x16x32_f16(A1m, Bh, d1, 0, 0, 0);
            d2 = __builtin_amdgcn_mfma_f32_16x16x32_f16(A2m, Bh, d2, 0, 0, 0);
            hp[0] = modrelu_pk(pk_rne(d1[0], d1[1]), bSp[0]);
            hp[1] = modrelu_pk(pk_rne(d1[2], d1[3]), bSp[1]);
            hp[2] = modrelu_pk(pk_rne(d2[0], d2[1]), bSp[2]);
            const uint32_t mr3 = modrelu_pk(pk_rne(d2[2], d2[3]), bSp[3]);
            // q3: next step's x (dead-state slot); tt=7's value is overwritten
            // before use at the next 8-group's injection, so &7 is safe.
            hp[3] = isq3 ? xpk[(tt + 1) & 7] : mr3;
        }
    };

    for (int s = 0; s < NSTAGE; ++s) {
        // ---- stage TCH steps of inputs for 8 batch rows into LDS ----
        // 8 rows * 28 float4 = 224 vector loads
        #pragma unroll
        for (int r = 0; r < 4; ++r) {
            const int idx = r * 64 + lane;
            if (idx < 224) {
                const int bl = idx / 28;
                const int t4 = idx % 28;
                const float4 v = *(const float4*)(inp + (size_t)(b0 + bl) * SEQ + s * TCH + t4 * 4);
                *(float4*)(&xs_lds[bl * XPAD + t4 * 4]) = v;
            }
        }
        __syncthreads();

        // cols 8..15 mirror cols 0..7 (keeps their state bounded; harmless --
        // columns never interact and output is guarded to n<8)
        const float* xrow = &xs_lds[(n & 7) * XPAD];
        float4 xv0 = *(const float4*)(xrow);
        float4 xv1 = *(const float4*)(xrow + 4);

        for (int t16 = 0; t16 < 7; ++t16) {   // 7 * 16 = 112 steps per stage
            // ---- APPLY pending scale (computed from state 16 steps ago) ----
            const uint32_t sc32 = (uint32_t)pend_field * 0x04000400u;  // f16x2 2^(field-15)
            #pragma unroll
            for (int p = 0; p < 4; ++p) hp[p] = scale_mul(hp[p], sc32);
            #pragma unroll
            for (int p = 0; p < 4; ++p) bSp[p] = scale_mul(bSp[p], sc32);
            xinv_e += pend_field - 15;

            // x scale into state space (constant for the whole 16-step window)
            const float fac = __uint_as_float((uint32_t)(127 + xinv_e) << 23);

            // ===== first 8-step half =====
            {
                const int toff = t16 * 16 + 8;    // second half's x (always in range)
                const float4 xn0 = *(const float4*)(xrow + toff);
                const float4 xn1 = *(const float4*)(xrow + toff + 4);

                uint32_t xpk[8];
                xpk[0] = pkrtz(xv0.x * fac, 0.f); xpk[1] = pkrtz(xv0.y * fac, 0.f);
                xpk[2] = pkrtz(xv0.z * fac, 0.f); xpk[3] = pkrtz(xv0.w * fac, 0.f);
                xpk[4] = pkrtz(xv1.x * fac, 0.f); xpk[5] = pkrtz(xv1.y * fac, 0.f);
                xpk[6] = pkrtz(xv1.z * fac, 0.f); xpk[7] = pkrtz(xv1.w * fac, 0.f);
                hp[3] = isq3 ? xpk[0] : hp[3];   // q3: step-0 x into the B-frag x slot

                // ---- SAMPLE max for the NEXT window (16-step staleness is safe:
                // overflow would need ~2^20 growth in 16 steps; measured ~2^2) ----
                {
                    uint32_t mx = pkmax(pkmax(hp[0] & 0x7FFF7FFFu, hp[1] & 0x7FFF7FFFu),
                                        pkmax(hp[2] & 0x7FFF7FFFu, hp[3] & 0x7FFF7FFFu));
                    mx = pkmax(mx, (uint32_t)__shfl_xor((int)mx, 16));
                    mx = pkmax(mx, (uint32_t)__shfl_xor((int)mx, 32));
                    // positive f16 bit patterns are order-isomorphic to values
                    const uint32_t e16 = max(mx & 0xFFFFu, mx >> 16);
                    const int e_raw = (int)(e16 >> 10);             // f16 exponent field
                    // target max -> [2^-5, 2^-4): sc = 2^(10-e_raw); clamp [2^-14, 2^5]
                    pend_field = min(max(25 - e_raw, 1), 20);
                }

                do8(xpk);
                xv0 = xn0;
                xv1 = xn1;
            }

            // ===== second 8-step half (same fac; no renorm) =====
            {
                const int toff = (t16 < 6) ? (t16 + 1) * 16 : 0;   // dummy 0 on last
                const float4 xn0 = *(const float4*)(xrow + toff);
                const float4 xn1 = *(const float4*)(xrow + toff + 4);

                uint32_t xpk[8];
                xpk[0] = pkrtz(xv0.x * fac, 0.f); xpk[1] = pkrtz(xv0.y * fac, 0.f);
                xpk[2] = pkrtz(xv0.z * fac, 0.f); xpk[3] = pkrtz(xv0.w * fac, 0.f);
                xpk[4] = pkrtz(xv1.x * fac, 0.f); xpk[5] = pkrtz(xv1.y * fac, 0.f);
                xpk[6] = pkrtz(xv1.z * fac, 0.f); xpk[7] = pkrtz(xv1.w * fac, 0.f);
                hp[3] = isq3 ? xpk[0] : hp[3];

                do8(xpk);
                xv0 = xn0;
                xv1 = xn1;
            }
        }
        __syncthreads();
    }

    // ---- final linear: logits = S * (h_hat @ W_lin^T) + b_lin, S = 2^(-xinv_e) ----
    const float S = __uint_as_float((uint32_t)(127 - xinv_e) << 23);
    float hf[8];
    #pragma unroll
    for (int p = 0; p < 4; ++p) {
        const f16x2 v = __builtin_bit_cast(f16x2, hp[p]);
        hf[2 * p] = (float)v.x;
        hf[2 * p + 1] = (float)v.y;
    }
    float acc[NCLS];
    #pragma unroll
    for (int c = 0; c < NCLS; ++c) {
        float p = 0.f;
        #pragma unroll
        for (int k = 0; k < 8; ++k) {
            const int j = 8 * q + k;
            if (j < HID) p += W_lin[c * HID + j] * hf[k];
        }
        p += __shfl_xor(p, 16, 64);
        p += __shfl_xor(p, 32, 64);
        acc[c] = p * S + b_lin[c];
    }
    if (q == 0 && n < 8) {
        #pragma unroll
        for (int c = 0; c < NCLS; ++c)
            out[(size_t)(b0 + n) * NCLS + c] = acc[c];
    }
}

extern "C" void kernel_launch(void* const* d_in, const int* in_sizes, int n_in,
                              void* d_out, int out_size, void* d_ws, size_t ws_size,
                              hipStream_t stream) {
    const float* inp   = (const float*)d_in[0];
    const float* W_ih  = (const float*)d_in[1];
    const float* W_hh  = (const float*)d_in[2];
    const float* b_mod = (const float*)d_in[3];
    const float* W_lin = (const float*)d_in[4];
    const float* b_lin = (const float*)d_in[5];
    float* out = (float*)d_out;

    dim3 grid(NBATCH / 8);  // 2048 blocks x 1 wave, 8 batch rows each -> 2 waves/SIMD
    dim3 block(64);
    hipLaunchKernelGGL(rnn_scan_kernel, grid, block, 0, stream,
                       inp, W_ih, W_hh, b_mod, W_lin, b_lin, out);
}

// Round 5
// 191.159 us; speedup vs baseline: 1.3972x; 1.1483x over previous
//
#include <hip/hip_runtime.h>
#include <stdint.h>

#define HID 30
#define NCLS 10
#define SEQ 784
#define NBATCH 16384
#define TCH 112      // time steps per LDS stage
#define NSTAGE 7     // 7 * 112 = 784
#define XPAD 116     // padded LDS row stride in floats

typedef _Float16 f16x8 __attribute__((ext_vector_type(8)));
typedef _Float16 f16x2 __attribute__((ext_vector_type(2)));
typedef float f32x4 __attribute__((ext_vector_type(4)));
typedef uint32_t u32x4 __attribute__((ext_vector_type(4)));

static __device__ __forceinline__ f16x8 mkfrag16(uint32_t a, uint32_t b, uint32_t c, uint32_t d) {
    u32x4 t = {a, b, c, d};
    return __builtin_bit_cast(f16x8, t);
}

static __device__ __forceinline__ uint32_t pkf16(_Float16 lo, _Float16 hi) {
    f16x2 v = {lo, hi};
    return __builtin_bit_cast(uint32_t, v);
}

// RNE f32->f16 pair pack. RNE is REQUIRED on the recurrent path (R8: RTZ+bias
// compensation diverged 100x).
static __device__ __forceinline__ uint32_t pk_rne(float a, float b) {
    return pkf16((_Float16)a, (_Float16)b);
}

// RTZ fine for one-shot x injection (non-recurrent)
static __device__ __forceinline__ uint32_t pkrtz(float a, float b) {
    return __builtin_bit_cast(uint32_t, __builtin_amdgcn_cvt_pkrtz(a, b));
}

// packed modReLU on an f16 pair: h = sign(z) * max(|z| + b, 0)
static __device__ __forceinline__ uint32_t modrelu_pk(uint32_t z, uint32_t bp) {
    const f16x2 zero2 = {(_Float16)0.f, (_Float16)0.f};
    f16x2 t = __builtin_bit_cast(f16x2, z & 0x7FFF7FFFu) + __builtin_bit_cast(f16x2, bp);
    t = __builtin_elementwise_max(t, zero2);
    const uint32_t tb = __builtin_bit_cast(uint32_t, t);
    return (tb & 0x7FFF7FFFu) | (z & 0x80008000u);   // -> v_bfi_b32
}

static __device__ __forceinline__ uint32_t pkmax(uint32_t a, uint32_t b) {
    return __builtin_bit_cast(uint32_t,
        __builtin_elementwise_max(__builtin_bit_cast(f16x2, a), __builtin_bit_cast(f16x2, b)));
}

static __device__ __forceinline__ uint32_t scale_mul(uint32_t v, uint32_t sc32) {
    return __builtin_bit_cast(uint32_t,
        __builtin_bit_cast(f16x2, v) * __builtin_bit_cast(f16x2, sc32));
}

// R12: back to the verified 16-col/wave structure (1024 blocks, 1 wave/SIMD).
// R10/R11 pinned the budget: issue demand D ~= 245 cy/step, wall 350 -> ~105 cy
// wave-private stall. Two stall cuts, numerics otherwise identical:
//  (1) de-chain hi/mid MFMAs: for a SINGLE wave, C-chaining serializes on the
//      first MFMA's full result latency (m119's full-rate chaining had >=2
//      waves/SIMD hiding it). Issue all 4 independently, sum in f32 VALU
//      (adds ~2^-23 reorder noise, 3 orders below the tolerated f16 rounding).
//  (2) split the max-sampler shfl butterfly across the two do8 halves so the
//      ~60cy DS latency of each shuffle hides under ~8 steps of compute
//      (structure verified correct in R9/R10).
__launch_bounds__(64, 1)
__global__ void rnn_scan_kernel(const float* __restrict__ inp,
                                const float* __restrict__ W_ih,
                                const float* __restrict__ W_hh,
                                const float* __restrict__ b_mod,
                                const float* __restrict__ W_lin,
                                const float* __restrict__ b_lin,
                                float* __restrict__ out)
{
    __shared__ __align__(16) float xs_lds[16 * XPAD];

    const int lane = threadIdx.x;   // one wave per block
    const int q = lane >> 4;        // k-quad: lane holds k = 8q..8q+7 of A/B frags
    const int n = lane & 15;        // batch column within the wave's 16-batch tile
    const int b0 = blockIdx.x * 16;

    // ---- A fragments: W_aug [32x32], row-permuted so D->B is lane-local ----
    // W_aug[i][j] = W_hh[i][j] (i,j<30); W_aug[i][30] = W_ih[i]; else 0.
    // A = Ah + Am (2-way f16 RNE split, ~21-bit; weight error systematic)
    const int i1 = 8 * (n >> 2) + (n & 3);
    const int i2 = i1 + 4;

    uint32_t a1h[4], a1m[4], a2h[4], a2m[4];
    #pragma unroll
    for (int p = 0; p < 4; ++p) {
        _Float16 h1[2], m1[2], h2[2], m2[2];
        #pragma unroll
        for (int e = 0; e < 2; ++e) {
            const int j = 8 * q + 2 * p + e;
            float w1 = 0.f, w2 = 0.f;
            if (j < HID) {
                w1 = W_hh[i1 * HID + j];
                if (i2 < HID) w2 = W_hh[i2 * HID + j];
            } else if (j == HID) {
                w1 = W_ih[i1];
                if (i2 < HID) w2 = W_ih[i2];
            }
            h1[e] = (_Float16)w1; m1[e] = (_Float16)(w1 - (float)h1[e]);
            h2[e] = (_Float16)w2; m2[e] = (_Float16)(w2 - (float)h2[e]);
        }
        a1h[p] = pkf16(h1[0], h1[1]); a1m[p] = pkf16(m1[0], m1[1]);
        a2h[p] = pkf16(h2[0], h2[1]); a2m[p] = pkf16(m2[0], m2[1]);
    }
    const f16x8 A1h = mkfrag16(a1h[0], a1h[1], a1h[2], a1h[3]);
    const f16x8 A1m = mkfrag16(a1m[0], a1m[1], a1m[2], a1m[3]);
    const f16x8 A2h = mkfrag16(a2h[0], a2h[1], a2h[2], a2h[3]);
    const f16x8 A2m = mkfrag16(a2m[0], a2m[1], a2m[2], a2m[3]);

    // b_mod packed pairs for this lane's 8 output rows (f16, scaled space b/S)
    uint32_t bSp[4];
    #pragma unroll
    for (int p = 0; p < 4; ++p) {
        const int ja = 8 * q + 2 * p;
        const int jb = ja + 1;
        const float ba = (ja < HID) ? b_mod[ja] : 0.f;
        const float bb = (jb < HID) ? b_mod[jb] : 0.f;
        bSp[p] = pk_rne(ba, bb);
    }

    // packed f16 state: hp[p] = (h[8q+2p], h[8q+2p+1]) in scaled space.
    // True h = S * h_hat, S = 2^(-xinv_e) per column. q3's hp[3] (rows 30,31 =
    // zero rows of W_aug) is dead state, reused as the x-injection slot so the
    // persistent state quad IS the MFMA B fragment.
    uint32_t hp[4] = {0u, 0u, 0u, 0u};
    int xinv_e = 0;
    int pend_field = 15;   // pending scale sc = 2^(field-15); identity for window 0

    const bool isq3 = (q == 3);
    const f32x4 z4 = {0.f, 0.f, 0.f, 0.f};

    // 8 recurrence steps using x values xpk[0..7].
    // De-chained: 4 independent MFMAs issue back-to-back, then 2 packed f32
    // vector adds combine hi+mid -- removes one MFMA result latency from the
    // serial per-step critical path (single-wave C-chaining is NOT free).
    auto do8 = [&](const uint32_t* xpk) {
        #pragma unroll
        for (int tt = 0; tt < 8; ++tt) {
            const f16x8 Bh = mkfrag16(hp[0], hp[1], hp[2], hp[3]);
            const f32x4 d1a = __builtin_amdgcn_mfma_f32_16x16x32_f16(A1h, Bh, z4, 0, 0, 0);
            const f32x4 d2a = __builtin_amdgcn_mfma_f32_16x16x32_f16(A2h, Bh, z4, 0, 0, 0);
            const f32x4 d1b = __builtin_amdgcn_mfma_f32_16x16x32_f16(A1m, Bh, z4, 0, 0, 0);
            const f32x4 d2b = __builtin_amdgcn_mfma_f32_16x16x32_f16(A2m, Bh, z4, 0, 0, 0);
            const f32x4 d1 = d1a + d1b;   // 2x v_pk_add_f32
            const f32x4 d2 = d2a + d2b;
            hp[0] = modrelu_pk(pk_rne(d1[0], d1[1]), bSp[0]);
            hp[1] = modrelu_pk(pk_rne(d1[2], d1[3]), bSp[1]);
            hp[2] = modrelu_pk(pk_rne(d2[0], d2[1]), bSp[2]);
            const uint32_t mr3 = modrelu_pk(pk_rne(d2[2], d2[3]), bSp[3]);
            // q3: next step's x (dead-state slot); tt=7's value is overwritten
            // before use at the next 8-group's injection, so &7 is safe.
            hp[3] = isq3 ? xpk[(tt + 1) & 7] : mr3;
        }
    };

    for (int s = 0; s < NSTAGE; ++s) {
        // ---- stage TCH steps of inputs for 16 batch rows into LDS ----
        #pragma unroll
        for (int r = 0; r < 7; ++r) {
            const int idx = r * 64 + lane;
            const int bl = idx / 28;
            const int t4 = idx % 28;
            const float4 v = *(const float4*)(inp + (size_t)(b0 + bl) * SEQ + s * TCH + t4 * 4);
            *(float4*)(&xs_lds[bl * XPAD + t4 * 4]) = v;
        }
        __syncthreads();

        const float* xrow = &xs_lds[n * XPAD];
        float4 xv0 = *(const float4*)(xrow);
        float4 xv1 = *(const float4*)(xrow + 4);

        for (int t16 = 0; t16 < 7; ++t16) {   // 7 * 16 = 112 steps per stage
            // ---- APPLY pending scale (computed from state 16 steps ago) ----
            const uint32_t sc32 = (uint32_t)pend_field * 0x04000400u;  // f16x2 2^(field-15)
            #pragma unroll
            for (int p = 0; p < 4; ++p) hp[p] = scale_mul(hp[p], sc32);
            #pragma unroll
            for (int p = 0; p < 4; ++p) bSp[p] = scale_mul(bSp[p], sc32);
            xinv_e += pend_field - 15;

            // x scale into state space (constant for the whole 16-step window)
            const float fac = __uint_as_float((uint32_t)(127 + xinv_e) << 23);

            uint32_t mx;

            // ===== first 8-step half =====
            {
                const int toff = t16 * 16 + 8;    // second half's x (always in range)
                const float4 xn0 = *(const float4*)(xrow + toff);
                const float4 xn1 = *(const float4*)(xrow + toff + 4);

                uint32_t xpk[8];
                xpk[0] = pkrtz(xv0.x * fac, 0.f); xpk[1] = pkrtz(xv0.y * fac, 0.f);
                xpk[2] = pkrtz(xv0.z * fac, 0.f); xpk[3] = pkrtz(xv0.w * fac, 0.f);
                xpk[4] = pkrtz(xv1.x * fac, 0.f); xpk[5] = pkrtz(xv1.y * fac, 0.f);
                xpk[6] = pkrtz(xv1.z * fac, 0.f); xpk[7] = pkrtz(xv1.w * fac, 0.f);
                hp[3] = isq3 ? xpk[0] : hp[3];   // q3: step-0 x into the B-frag x slot

                // ---- SAMPLE max for the NEXT window (16-step staleness is safe:
                // overflow would need ~2^20 growth in 16 steps; measured ~2^2).
                // Butterfly split across the window: each shfl issues ~8 steps
                // before its consumer so DS latency hides under do8. ----
                mx = pkmax(pkmax(hp[0] & 0x7FFF7FFFu, hp[1] & 0x7FFF7FFFu),
                           pkmax(hp[2] & 0x7FFF7FFFu, hp[3] & 0x7FFF7FFFu));
                const uint32_t sh1 = (uint32_t)__shfl_xor((int)mx, 16);

                do8(xpk);

                mx = pkmax(mx, sh1);
                xv0 = xn0;
                xv1 = xn1;
            }
            const uint32_t sh2 = (uint32_t)__shfl_xor((int)mx, 32);

            // ===== second 8-step half (same fac; no renorm) =====
            {
                const int toff = (t16 < 6) ? (t16 + 1) * 16 : 0;   // dummy 0 on last
                const float4 xn0 = *(const float4*)(xrow + toff);
                const float4 xn1 = *(const float4*)(xrow + toff + 4);

                uint32_t xpk[8];
                xpk[0] = pkrtz(xv0.x * fac, 0.f); xpk[1] = pkrtz(xv0.y * fac, 0.f);
                xpk[2] = pkrtz(xv0.z * fac, 0.f); xpk[3] = pkrtz(xv0.w * fac, 0.f);
                xpk[4] = pkrtz(xv1.x * fac, 0.f); xpk[5] = pkrtz(xv1.y * fac, 0.f);
                xpk[6] = pkrtz(xv1.z * fac, 0.f); xpk[7] = pkrtz(xv1.w * fac, 0.f);
                hp[3] = isq3 ? xpk[0] : hp[3];

                do8(xpk);

                xv0 = xn0;
                xv1 = xn1;
            }

            // finish butterfly, derive next window's pending scale field
            mx = pkmax(mx, sh2);
            // positive f16 bit patterns are order-isomorphic to values
            const uint32_t e16 = max(mx & 0xFFFFu, mx >> 16);
            const int e_raw = (int)(e16 >> 10);             // f16 exponent field
            // target max -> [2^-5, 2^-4): sc = 2^(10-e_raw); clamp [2^-14, 2^5]
            pend_field = min(max(25 - e_raw, 1), 20);
        }
        __syncthreads();
    }

    // ---- final linear: logits = S * (h_hat @ W_lin^T) + b_lin, S = 2^(-xinv_e) ----
    const float S = __uint_as_float((uint32_t)(127 - xinv_e) << 23);
    float hf[8];
    #pragma unroll
    for (int p = 0; p < 4; ++p) {
        const f16x2 v = __builtin_bit_cast(f16x2, hp[p]);
        hf[2 * p] = (float)v.x;
        hf[2 * p + 1] = (float)v.y;
    }
    float acc[NCLS];
    #pragma unroll
    for (int c = 0; c < NCLS; ++c) {
        float p = 0.f;
        #pragma unroll
        for (int k = 0; k < 8; ++k) {
            const int j = 8 * q + k;
            if (j < HID) p += W_lin[c * HID + j] * hf[k];
        }
        p += __shfl_xor(p, 16, 64);
        p += __shfl_xor(p, 32, 64);
        acc[c] = p * S + b_lin[c];
    }
    if (q == 0) {
        #pragma unroll
        for (int c = 0; c < NCLS; ++c)
            out[(size_t)(b0 + n) * NCLS + c] = acc[c];
    }
}

extern "C" void kernel_launch(void* const* d_in, const int* in_sizes, int n_in,
                              void* d_out, int out_size, void* d_ws, size_t ws_size,
                              hipStream_t stream) {
    const float* inp   = (const float*)d_in[0];
    const float* W_ih  = (const float*)d_in[1];
    const float* W_hh  = (const float*)d_in[2];
    const float* b_mod = (const float*)d_in[3];
    const float* W_lin = (const float*)d_in[4];
    const float* b_lin = (const float*)d_in[5];
    float* out = (float*)d_out;

    dim3 grid(NBATCH / 16);  // 1024 blocks x 1 wave, 16 batch rows each
    dim3 block(64);
    hipLaunchKernelGGL(rnn_scan_kernel, grid, block, 0, stream,
                       inp, W_ih, W_hh, b_mod, W_lin, b_lin, out);
}